// Round 17
// baseline (100.611 us; speedup 1.0000x reference)
//
#include <hip/hip_runtime.h>
#include <hip/hip_bf16.h>

typedef __attribute__((ext_vector_type(8))) short short8;
typedef __attribute__((ext_vector_type(4))) short short4v;
typedef __attribute__((ext_vector_type(16))) float f32x16;

constexpr int Bc = 4;
constexpr int Lc = 2048;
constexpr int Sc = 2048;
constexpr int Hc = 16;
constexpr int Ec = 64;
constexpr int Dc = 64;
constexpr int QBLK = 128;   // 4 waves x 32 q-rows, ONE tile per block (thin: ~160 regs -> 3 waves/SIMD)
constexpr int KBLK = 64;
constexpr int NQT  = Lc / QBLK;   // 16 q-tiles

__device__ __forceinline__ unsigned short b16(float x) {
  __bf16 h = (__bf16)x;
  return __builtin_bit_cast(unsigned short, h);
}
__device__ __forceinline__ unsigned pk2(float lo, float hi) {
  return (unsigned)b16(lo) | ((unsigned)b16(hi) << 16);
}
__device__ __forceinline__ short8 cvt8(float4 a, float4 b) {
  short8 w;
  w[0] = (short)b16(a.x); w[1] = (short)b16(a.y);
  w[2] = (short)b16(a.z); w[3] = (short)b16(a.w);
  w[4] = (short)b16(b.x); w[5] = (short)b16(b.y);
  w[6] = (short)b16(b.z); w[7] = (short)b16(b.w);
  return w;
}
__device__ __forceinline__ short8 mk8(unsigned d0, unsigned d1, unsigned d2, unsigned d3) {
  union { unsigned u[4]; short8 s; } t;
  t.u[0] = d0; t.u[1] = d1; t.u[2] = d2; t.u[3] = d3;
  return t.s;
}
__device__ __forceinline__ float max3f(float a, float b, float c) {
  return fmaxf(fmaxf(a, b), c);   // clang fuses to v_max3_f32
}

struct KV { float4 k[4]; float4 v[4]; };

__global__ __launch_bounds__(256, 2)
void fattn_kernel(const float* __restrict__ Qg, const float* __restrict__ Kg,
                  const float* __restrict__ Vg, float* __restrict__ Og) {
  __shared__ unsigned short Kl[2][KBLK * 64];
  __shared__ unsigned short Vl[2][KBLK * 64];

  const int tid  = (int)threadIdx.x;
  const int wave = tid >> 6;
  const int lane = tid & 63;
  const int q32  = lane & 31;
  const int hi   = lane >> 5;

  // XCD-aware (T1): x = bh (64) fastest -> XCD = bh % 8 (all q-tiles of one bh
  // share one XCD's L2). y = pb with qtile = NQT-1-pb -> heavy tiles dispatch
  // FIRST; at 3 blocks/CU (768 slots < 1024 blocks) light tiles backfill.
  const int bh = (int)blockIdx.x;
  const int pb = (int)blockIdx.y;
  const int b  = bh >> 4;
  const int h  = bh & 15;

  const int qtile = NQT - 1 - pb;
  const int q0w   = qtile * QBLK + wave * 32;
  const int nch   = 2 * qtile + 2;

  const float QSCALE = 0.125f * 1.44269504088896341f;  // 1/sqrt(64) * log2(e)
  short8 qf[4];
  {
    const float* qp = Qg + (((size_t)(b * Lc + q0w + q32)) * Hc + h) * Ec;
#pragma unroll
    for (int c = 0; c < 4; ++c) {
      const float4* p4 = (const float4*)(qp + c * 16 + hi * 8);
      float4 x = p4[0], y = p4[1];
      x.x *= QSCALE; x.y *= QSCALE; x.z *= QSCALE; x.w *= QSCALE;
      y.x *= QSCALE; y.y *= QSCALE; y.z *= QSCALE; y.w *= QSCALE;
      qf[c] = cvt8(x, y);
    }
  }

  short8 ones;
#pragma unroll
  for (int j = 0; j < 8; ++j) ones[j] = (short)0x3F80;

  const int s  = tid >> 2;
  const int e0 = (tid & 3) << 4;

  auto loadKV = [&](int ch) {
    KV r;
    const size_t row = (((size_t)(b * Sc + ch * KBLK + s)) * Hc + h);
    const float4* kp4 = (const float4*)(Kg + row * Ec + e0);
    const float4* vp4 = (const float4*)(Vg + row * Dc + e0);
#pragma unroll
    for (int i = 0; i < 4; ++i) { r.k[i] = kp4[i]; r.v[i] = vp4[i]; }
    return r;
  };

  auto writeKV = [&](const KV& r, int buf) {
    short8 w0 = cvt8(r.k[0], r.k[1]);
    short8 w1 = cvt8(r.k[2], r.k[3]);
    const int c0 = e0 >> 3;
    *(short8*)&Kl[buf][s * 64 + (((c0    ) ^ (s & 7)) << 3)] = w0;
    *(short8*)&Kl[buf][s * 64 + (((c0 + 1) ^ (s & 7)) << 3)] = w1;
    short8 wv0 = cvt8(r.v[0], r.v[1]);
    short8 wv1 = cvt8(r.v[2], r.v[3]);
    const int vt = ((s >> 2) * 4 + (tid & 3)) * 64 + (s & 3) * 16;
    *(short8*)&Vl[buf][vt]     = wv0;
    *(short8*)&Vl[buf][vt + 8] = wv1;
  };

  f32x16 acco0 = (f32x16)(0.f), acco1 = (f32x16)(0.f), accl = (f32x16)(0.f);
  float m_run = -1e30f;

  auto doTile = [&](int ch, int cur) {
    const int s0 = ch * 64;
    if (s0 > q0w) return;          // guard: chunk entirely in the future for this wave
    const bool act1  = (s0 + 32 <= q0w);
    const bool diag0 = (s0 == q0w);
    const bool diag1 = (s0 + 32 == q0w);

    auto qk = [&](int sb) {
      f32x16 acc = (f32x16)(0.f);
      const int sr = sb * 32 + q32;
      const int rb = sr * 64;
      const int sw = sr & 7;
#pragma unroll
      for (int c = 0; c < 4; ++c) {
        short8 kf = *(const short8*)&Kl[cur][rb + (((2 * c + hi) ^ sw) << 3)];
        acc = __builtin_amdgcn_mfma_f32_32x32x16_bf16(kf, qf[c], acc, 0, 0, 0);
      }
      return acc;
    };
    f32x16 S0 = qk(0);
    f32x16 S1;
    if (act1) S1 = qk(1);

    const int tq = q32 - 4 * hi;
    if (diag0) {
#pragma unroll
      for (int r = 0; r < 16; ++r)
        if (((r & 3) + 8 * (r >> 2)) > tq) S0[r] = -1e30f;
    }
    if (act1 && diag1) {
#pragma unroll
      for (int r = 0; r < 16; ++r)
        if (((r & 3) + 8 * (r >> 2)) > tq) S1[r] = -1e30f;
    }

    // ---- chunk max via v_max3 tree ----
    float pmax;
    {
      float t0 = max3f(S0[0],  S0[1],  S0[2]);
      float t1 = max3f(S0[3],  S0[4],  S0[5]);
      float t2 = max3f(S0[6],  S0[7],  S0[8]);
      float t3 = max3f(S0[9],  S0[10], S0[11]);
      float t4 = max3f(S0[12], S0[13], S0[14]);
      float u0 = max3f(t0, t1, t2);
      float u1 = max3f(t3, t4, S0[15]);
      pmax = fmaxf(u0, u1);
      if (act1) {
        float v0 = max3f(S1[0],  S1[1],  S1[2]);
        float v1 = max3f(S1[3],  S1[4],  S1[5]);
        float v2 = max3f(S1[6],  S1[7],  S1[8]);
        float v3 = max3f(S1[9],  S1[10], S1[11]);
        float v4 = max3f(S1[12], S1[13], S1[14]);
        float w0 = max3f(v0, v1, v2);
        float w1 = max3f(v3, v4, S1[15]);
        pmax = max3f(pmax, w0, w1);
      }
    }
    {
      unsigned px = __builtin_bit_cast(unsigned, pmax);
      auto sw = __builtin_amdgcn_permlane32_swap(px, px, false, false);
      pmax = fmaxf(__builtin_bit_cast(float, (unsigned)sw[0]),
                   __builtin_bit_cast(float, (unsigned)sw[1]));
    }

    if (!__all(pmax - m_run <= 8.0f)) {
      const float mnew  = fmaxf(m_run, pmax);
      const float alpha = exp2f(m_run - mnew);
      m_run = mnew;
      const int hib = hi << 4;
      const int av  = __builtin_bit_cast(int, alpha);
#pragma unroll
      for (int r = 0; r < 16; ++r) {
        const int addr = hib + 4 * ((r & 3) + 8 * (r >> 2));
        float ar = __builtin_bit_cast(float, __builtin_amdgcn_ds_bpermute(addr, av));
        acco0[r] *= ar; acco1[r] *= ar; accl[r] *= ar;
      }
    }

#pragma unroll
    for (int r = 0; r < 16; ++r) S0[r] = exp2f(S0[r] - m_run);
    if (act1) {
#pragma unroll
      for (int r = 0; r < 16; ++r) S1[r] = exp2f(S1[r] - m_run);
    }

    auto mkpa = [&](const f32x16& P, int a, int bidx) {
      unsigned A0 = pk2(P[4 * a + 0],    P[4 * a + 1]);
      unsigned A1 = pk2(P[4 * a + 2],    P[4 * a + 3]);
      unsigned B0 = pk2(P[4 * bidx + 0], P[4 * bidx + 1]);
      unsigned B1 = pk2(P[4 * bidx + 2], P[4 * bidx + 3]);
      auto r0 = __builtin_amdgcn_permlane32_swap(A0, B0, false, false);
      auto r1 = __builtin_amdgcn_permlane32_swap(A1, B1, false, false);
      return mk8((unsigned)r0[0], (unsigned)r1[0], (unsigned)r0[1], (unsigned)r1[1]);
    };
    short8 pa0 = mkpa(S0, 0, 1);
    short8 pa1 = mkpa(S0, 2, 3);
    short8 pa2, pa3;
    if (act1) { pa2 = mkpa(S1, 0, 1); pa3 = mkpa(S1, 2, 3); }

    // ---- V transpose-reads: dt OUTER so the oldest 8 (or 4) reads are dt=0 ----
    const unsigned vbase = (unsigned)(size_t)(&Vl[cur][0]);
    const unsigned vcol  = ((unsigned)(q32 & 15) << 3);
    short4v vlo[2][4], vhi[2][4];
#pragma unroll
    for (int dt = 0; dt < 2; ++dt) {
#pragma unroll
      for (int ks = 0; ks < 4; ++ks) {
        if (ks < 2 || act1) {
          const unsigned a0 = vbase +
            ((((unsigned)(4 * ks + 2 * hi) * 4u) + 2u * dt + (unsigned)(q32 >> 4)) << 7) + vcol;
          asm volatile("ds_read_b64_tr_b16 %0, %1 offset:0"   : "=&v"(vlo[dt][ks]) : "v"(a0));
          asm volatile("ds_read_b64_tr_b16 %0, %1 offset:512" : "=&v"(vhi[dt][ks]) : "v"(a0));
        }
      }
    }

    // ---- denominators (MFMA pipe, no vf dependency; hides tr-read latency) ----
    accl = __builtin_amdgcn_mfma_f32_32x32x16_bf16(pa0, ones, accl, 0, 0, 0);
    accl = __builtin_amdgcn_mfma_f32_32x32x16_bf16(pa1, ones, accl, 0, 0, 0);
    if (act1) {
      accl = __builtin_amdgcn_mfma_f32_32x32x16_bf16(pa2, ones, accl, 0, 0, 0);
      accl = __builtin_amdgcn_mfma_f32_32x32x16_bf16(pa3, ones, accl, 0, 0, 0);
    }

    // ---- counted drain: start dt=0 PV once its reads are done ----
    if (act1) { asm volatile("s_waitcnt lgkmcnt(8)" ::: "memory"); }
    else      { asm volatile("s_waitcnt lgkmcnt(4)" ::: "memory"); }
    __builtin_amdgcn_sched_barrier(0);

    __builtin_amdgcn_s_setprio(1);
    {
      f32x16& ac = acco0;
      short8 vf0 = __builtin_shufflevector(vlo[0][0], vhi[0][0], 0,1,2,3,4,5,6,7);
      short8 vf1 = __builtin_shufflevector(vlo[0][1], vhi[0][1], 0,1,2,3,4,5,6,7);
      ac = __builtin_amdgcn_mfma_f32_32x32x16_bf16(pa0, vf0, ac, 0, 0, 0);
      ac = __builtin_amdgcn_mfma_f32_32x32x16_bf16(pa1, vf1, ac, 0, 0, 0);
      if (act1) {
        short8 vf2 = __builtin_shufflevector(vlo[0][2], vhi[0][2], 0,1,2,3,4,5,6,7);
        short8 vf3 = __builtin_shufflevector(vlo[0][3], vhi[0][3], 0,1,2,3,4,5,6,7);
        ac = __builtin_amdgcn_mfma_f32_32x32x16_bf16(pa2, vf2, ac, 0, 0, 0);
        ac = __builtin_amdgcn_mfma_f32_32x32x16_bf16(pa3, vf3, ac, 0, 0, 0);
      }
    }
    __builtin_amdgcn_s_setprio(0);

    asm volatile("s_waitcnt lgkmcnt(0)" ::: "memory");
    __builtin_amdgcn_sched_barrier(0);

    __builtin_amdgcn_s_setprio(1);
    {
      f32x16& ac = acco1;
      short8 vf0 = __builtin_shufflevector(vlo[1][0], vhi[1][0], 0,1,2,3,4,5,6,7);
      short8 vf1 = __builtin_shufflevector(vlo[1][1], vhi[1][1], 0,1,2,3,4,5,6,7);
      ac = __builtin_amdgcn_mfma_f32_32x32x16_bf16(pa0, vf0, ac, 0, 0, 0);
      ac = __builtin_amdgcn_mfma_f32_32x32x16_bf16(pa1, vf1, ac, 0, 0, 0);
      if (act1) {
        short8 vf2 = __builtin_shufflevector(vlo[1][2], vhi[1][2], 0,1,2,3,4,5,6,7);
        short8 vf3 = __builtin_shufflevector(vlo[1][3], vhi[1][3], 0,1,2,3,4,5,6,7);
        ac = __builtin_amdgcn_mfma_f32_32x32x16_bf16(pa2, vf2, ac, 0, 0, 0);
        ac = __builtin_amdgcn_mfma_f32_32x32x16_bf16(pa3, vf3, ac, 0, 0, 0);
      }
    }
    __builtin_amdgcn_s_setprio(0);
  };

  // prologue: stage chunk 0 into buf 0
  { KV r0 = loadKV(0); writeKV(r0, 0); }
  __syncthreads();

  int cur = 0;
  for (int ch = 0; ch < nch; ++ch) {
    const bool pref = (ch + 1 < nch);
    KV nxt;
    if (pref) nxt = loadKV(ch + 1);

    doTile(ch, cur);

    if (pref) writeKV(nxt, cur ^ 1);
    __syncthreads();
    cur ^= 1;
  }

  // ---- epilogue: O = acco / accl ----
#pragma unroll
  for (int r = 0; r < 16; ++r) {
    const int q_loc = (r & 3) + 8 * (r >> 2) + 4 * hi;
    const int q = q0w + q_loc;
    const float inv = 1.0f / accl[r];
    float* op = Og + (((size_t)(b * Lc + q)) * Hc + h) * Dc + q32;
    op[0]  = acco0[r] * inv;
    op[32] = acco1[r] * inv;
  }
}

extern "C" void kernel_launch(void* const* d_in, const int* in_sizes, int n_in,
                              void* d_out, int out_size, void* d_ws, size_t ws_size,
                              hipStream_t stream) {
  const float* Q = (const float*)d_in[0];
  const float* K = (const float*)d_in[1];
  const float* V = (const float*)d_in[2];
  float* O = (float*)d_out;
  dim3 grid(Bc * Hc, NQT);   // x = bh (XCD affinity), y = pb (heavy-first)
  fattn_kernel<<<grid, 256, 0, stream>>>(Q, K, V, O);
}

// Round 18
// 94.962 us; speedup vs baseline: 1.0595x; 1.0595x over previous
//
#include <hip/hip_runtime.h>
#include <hip/hip_bf16.h>

typedef __attribute__((ext_vector_type(8))) short short8;
typedef __attribute__((ext_vector_type(4))) short short4v;
typedef __attribute__((ext_vector_type(16))) float f32x16;

constexpr int Bc = 4;
constexpr int Lc = 2048;
constexpr int Sc = 2048;
constexpr int Hc = 16;
constexpr int Ec = 64;
constexpr int Dc = 64;
constexpr int QBLK = 128;   // per tile: 4 waves x 32 q-rows; each block owns TWO tiles
constexpr int KBLK = 64;
constexpr int NQT  = Lc / QBLK;   // 16 q-tiles -> 8 complementary pairs

__device__ __forceinline__ unsigned short b16(float x) {
  __bf16 h = (__bf16)x;
  return __builtin_bit_cast(unsigned short, h);
}
__device__ __forceinline__ unsigned pk2(float lo, float hi) {
  return (unsigned)b16(lo) | ((unsigned)b16(hi) << 16);
}
__device__ __forceinline__ short8 cvt8(float4 a, float4 b) {
  short8 w;
  w[0] = (short)b16(a.x); w[1] = (short)b16(a.y);
  w[2] = (short)b16(a.z); w[3] = (short)b16(a.w);
  w[4] = (short)b16(b.x); w[5] = (short)b16(b.y);
  w[6] = (short)b16(b.z); w[7] = (short)b16(b.w);
  return w;
}
__device__ __forceinline__ short8 mk8(unsigned d0, unsigned d1, unsigned d2, unsigned d3) {
  union { unsigned u[4]; short8 s; } t;
  t.u[0] = d0; t.u[1] = d1; t.u[2] = d2; t.u[3] = d3;
  return t.s;
}
__device__ __forceinline__ float max3f(float a, float b, float c) {
  return fmaxf(fmaxf(a, b), c);   // clang fuses to v_max3_f32
}

struct KV { float4 k[4]; float4 v[4]; };

__global__ __launch_bounds__(256, 2)
void fattn_kernel(const float* __restrict__ Qg, const float* __restrict__ Kg,
                  const float* __restrict__ Vg, float* __restrict__ Og) {
  __shared__ unsigned short Kl[2][KBLK * 64];
  __shared__ unsigned short Vl[2][KBLK * 64];

  const int tid  = (int)threadIdx.x;
  const int wave = tid >> 6;
  const int lane = tid & 63;
  const int q32  = lane & 31;
  const int hi   = lane >> 5;

  // XCD-aware mapping (T1): x = bh (64), y = pair (8).
  // linear id = bh + 64*pb -> XCD = bh % 8: all 8 pair-blocks of one bh share
  // one XCD's L2 and walk K/V chunks in lock-step -> 1 miss + 7 hits per chunk.
  const int bh = (int)blockIdx.x;
  const int pb = (int)blockIdx.y;
  const int b  = bh >> 4;
  const int h  = bh & 15;

  const int qA   = pb;            // light tile
  const int qB   = NQT - 1 - pb;  // heavy tile
  const int q0A  = qA * QBLK + wave * 32;
  const int q0B  = qB * QBLK + wave * 32;
  const int nchA = 2 * pb + 2;
  const int nchB = 2 * qB + 2;    // >= nchA

  const float QSCALE = 0.125f * 1.44269504088896341f;  // 1/sqrt(64) * log2(e)
  auto loadQ = [&](int q0, short8 (&qf)[4]) {
    const float* qp = Qg + (((size_t)(b * Lc + q0 + q32)) * Hc + h) * Ec;
#pragma unroll
    for (int c = 0; c < 4; ++c) {
      const float4* p4 = (const float4*)(qp + c * 16 + hi * 8);
      float4 x = p4[0], y = p4[1];
      x.x *= QSCALE; x.y *= QSCALE; x.z *= QSCALE; x.w *= QSCALE;
      y.x *= QSCALE; y.y *= QSCALE; y.z *= QSCALE; y.w *= QSCALE;
      qf[c] = cvt8(x, y);
    }
  };
  short8 qfA[4], qfB[4];
  loadQ(q0A, qfA);
  loadQ(q0B, qfB);

  short8 ones;
#pragma unroll
  for (int j = 0; j < 8; ++j) ones[j] = (short)0x3F80;

  const int s  = tid >> 2;
  const int e0 = (tid & 3) << 4;

  auto loadKV = [&](int ch) {
    KV r;
    const size_t row = (((size_t)(b * Sc + ch * KBLK + s)) * Hc + h);
    const float4* kp4 = (const float4*)(Kg + row * Ec + e0);
    const float4* vp4 = (const float4*)(Vg + row * Dc + e0);
#pragma unroll
    for (int i = 0; i < 4; ++i) { r.k[i] = kp4[i]; r.v[i] = vp4[i]; }
    return r;
  };

  auto writeKV = [&](const KV& r, int buf) {
    short8 w0 = cvt8(r.k[0], r.k[1]);
    short8 w1 = cvt8(r.k[2], r.k[3]);
    const int c0 = e0 >> 3;
    *(short8*)&Kl[buf][s * 64 + (((c0    ) ^ (s & 7)) << 3)] = w0;
    *(short8*)&Kl[buf][s * 64 + (((c0 + 1) ^ (s & 7)) << 3)] = w1;
    short8 wv0 = cvt8(r.v[0], r.v[1]);
    short8 wv1 = cvt8(r.v[2], r.v[3]);
    const int vt = ((s >> 2) * 4 + (tid & 3)) * 64 + (s & 3) * 16;
    *(short8*)&Vl[buf][vt]     = wv0;
    *(short8*)&Vl[buf][vt + 8] = wv1;
  };

  f32x16 accoA0 = (f32x16)(0.f), accoA1 = (f32x16)(0.f), acclA = (f32x16)(0.f);
  f32x16 accoB0 = (f32x16)(0.f), accoB1 = (f32x16)(0.f), acclB = (f32x16)(0.f);
  float mA = -1e30f, mB = -1e30f;

  auto doTile = [&](int ch, int cur, int q0w, const short8 (&qf)[4],
                    f32x16& acco0, f32x16& acco1, f32x16& accl, float& m_run) {
    const int s0 = ch * 64;
    const bool act0 = (s0 <= q0w);
    if (!act0) return;
    const bool act1  = (s0 + 32 <= q0w);
    const bool diag0 = (s0 == q0w);
    const bool diag1 = (s0 + 32 == q0w);

    auto qk = [&](int sb) {
      f32x16 acc = (f32x16)(0.f);
      const int sr = sb * 32 + q32;
      const int rb = sr * 64;
      const int sw = sr & 7;
#pragma unroll
      for (int c = 0; c < 4; ++c) {
        short8 kf = *(const short8*)&Kl[cur][rb + (((2 * c + hi) ^ sw) << 3)];
        acc = __builtin_amdgcn_mfma_f32_32x32x16_bf16(kf, qf[c], acc, 0, 0, 0);
      }
      return acc;
    };
    f32x16 S0 = qk(0);
    f32x16 S1;
    if (act1) S1 = qk(1);

    const int tq = q32 - 4 * hi;
    if (diag0) {
#pragma unroll
      for (int r = 0; r < 16; ++r)
        if (((r & 3) + 8 * (r >> 2)) > tq) S0[r] = -1e30f;
    }
    if (act1 && diag1) {
#pragma unroll
      for (int r = 0; r < 16; ++r)
        if (((r & 3) + 8 * (r >> 2)) > tq) S1[r] = -1e30f;
    }

    // ---- chunk max via v_max3 tree (short dep chain) ----
    float pmax;
    {
      float t0 = max3f(S0[0],  S0[1],  S0[2]);
      float t1 = max3f(S0[3],  S0[4],  S0[5]);
      float t2 = max3f(S0[6],  S0[7],  S0[8]);
      float t3 = max3f(S0[9],  S0[10], S0[11]);
      float t4 = max3f(S0[12], S0[13], S0[14]);
      float u0 = max3f(t0, t1, t2);
      float u1 = max3f(t3, t4, S0[15]);
      pmax = fmaxf(u0, u1);
      if (act1) {
        float v0 = max3f(S1[0],  S1[1],  S1[2]);
        float v1 = max3f(S1[3],  S1[4],  S1[5]);
        float v2 = max3f(S1[6],  S1[7],  S1[8]);
        float v3 = max3f(S1[9],  S1[10], S1[11]);
        float v4 = max3f(S1[12], S1[13], S1[14]);
        float w0 = max3f(v0, v1, v2);
        float w1 = max3f(v3, v4, S1[15]);
        pmax = max3f(pmax, w0, w1);
      }
    }
    {
      unsigned px = __builtin_bit_cast(unsigned, pmax);
      auto sw = __builtin_amdgcn_permlane32_swap(px, px, false, false);
      pmax = fmaxf(__builtin_bit_cast(float, (unsigned)sw[0]),
                   __builtin_bit_cast(float, (unsigned)sw[1]));
    }

    if (!__all(pmax - m_run <= 8.0f)) {
      const float mnew  = fmaxf(m_run, pmax);
      const float alpha = exp2f(m_run - mnew);
      m_run = mnew;
      const int hib = hi << 4;
      const int av  = __builtin_bit_cast(int, alpha);
#pragma unroll
      for (int r = 0; r < 16; ++r) {
        const int addr = hib + 4 * ((r & 3) + 8 * (r >> 2));
        float ar = __builtin_bit_cast(float, __builtin_amdgcn_ds_bpermute(addr, av));
        acco0[r] *= ar; acco1[r] *= ar; accl[r] *= ar;
      }
    }

#pragma unroll
    for (int r = 0; r < 16; ++r) S0[r] = exp2f(S0[r] - m_run);
    if (act1) {
#pragma unroll
      for (int r = 0; r < 16; ++r) S1[r] = exp2f(S1[r] - m_run);
    }

    auto mkpa = [&](const f32x16& P, int a, int bidx) {
      unsigned A0 = pk2(P[4 * a + 0],    P[4 * a + 1]);
      unsigned A1 = pk2(P[4 * a + 2],    P[4 * a + 3]);
      unsigned B0 = pk2(P[4 * bidx + 0], P[4 * bidx + 1]);
      unsigned B1 = pk2(P[4 * bidx + 2], P[4 * bidx + 3]);
      auto r0 = __builtin_amdgcn_permlane32_swap(A0, B0, false, false);
      auto r1 = __builtin_amdgcn_permlane32_swap(A1, B1, false, false);
      return mk8((unsigned)r0[0], (unsigned)r1[0], (unsigned)r0[1], (unsigned)r1[1]);
    };
    short8 pa0 = mkpa(S0, 0, 1);
    short8 pa1 = mkpa(S0, 2, 3);
    short8 pa2, pa3;
    if (act1) { pa2 = mkpa(S1, 0, 1); pa3 = mkpa(S1, 2, 3); }

    // ---- V transpose-reads: dt OUTER so the oldest 8 (or 4) reads are dt=0 ----
    const unsigned vbase = (unsigned)(size_t)(&Vl[cur][0]);
    const unsigned vcol  = ((unsigned)(q32 & 15) << 3);
    short4v vlo[2][4], vhi[2][4];
#pragma unroll
    for (int dt = 0; dt < 2; ++dt) {
#pragma unroll
      for (int ks = 0; ks < 4; ++ks) {
        if (ks < 2 || act1) {
          const unsigned a0 = vbase +
            ((((unsigned)(4 * ks + 2 * hi) * 4u) + 2u * dt + (unsigned)(q32 >> 4)) << 7) + vcol;
          asm volatile("ds_read_b64_tr_b16 %0, %1 offset:0"   : "=&v"(vlo[dt][ks]) : "v"(a0));
          asm volatile("ds_read_b64_tr_b16 %0, %1 offset:512" : "=&v"(vhi[dt][ks]) : "v"(a0));
        }
      }
    }

    // ---- denominators (MFMA pipe, no vf dependency; hides tr-read latency) ----
    accl = __builtin_amdgcn_mfma_f32_32x32x16_bf16(pa0, ones, accl, 0, 0, 0);
    accl = __builtin_amdgcn_mfma_f32_32x32x16_bf16(pa1, ones, accl, 0, 0, 0);
    if (act1) {
      accl = __builtin_amdgcn_mfma_f32_32x32x16_bf16(pa2, ones, accl, 0, 0, 0);
      accl = __builtin_amdgcn_mfma_f32_32x32x16_bf16(pa3, ones, accl, 0, 0, 0);
    }

    // ---- counted drain: start dt=0 PV once its 8 (or 4) reads are done ----
    if (act1) { asm volatile("s_waitcnt lgkmcnt(8)" ::: "memory"); }
    else      { asm volatile("s_waitcnt lgkmcnt(4)" ::: "memory"); }
    __builtin_amdgcn_sched_barrier(0);

    __builtin_amdgcn_s_setprio(1);
    {
      f32x16& ac = acco0;
      short8 vf0 = __builtin_shufflevector(vlo[0][0], vhi[0][0], 0,1,2,3,4,5,6,7);
      short8 vf1 = __builtin_shufflevector(vlo[0][1], vhi[0][1], 0,1,2,3,4,5,6,7);
      ac = __builtin_amdgcn_mfma_f32_32x32x16_bf16(pa0, vf0, ac, 0, 0, 0);
      ac = __builtin_amdgcn_mfma_f32_32x32x16_bf16(pa1, vf1, ac, 0, 0, 0);
      if (act1) {
        short8 vf2 = __builtin_shufflevector(vlo[0][2], vhi[0][2], 0,1,2,3,4,5,6,7);
        short8 vf3 = __builtin_shufflevector(vlo[0][3], vhi[0][3], 0,1,2,3,4,5,6,7);
        ac = __builtin_amdgcn_mfma_f32_32x32x16_bf16(pa2, vf2, ac, 0, 0, 0);
        ac = __builtin_amdgcn_mfma_f32_32x32x16_bf16(pa3, vf3, ac, 0, 0, 0);
      }
    }
    __builtin_amdgcn_s_setprio(0);

    asm volatile("s_waitcnt lgkmcnt(0)" ::: "memory");
    __builtin_amdgcn_sched_barrier(0);

    __builtin_amdgcn_s_setprio(1);
    {
      f32x16& ac = acco1;
      short8 vf0 = __builtin_shufflevector(vlo[1][0], vhi[1][0], 0,1,2,3,4,5,6,7);
      short8 vf1 = __builtin_shufflevector(vlo[1][1], vhi[1][1], 0,1,2,3,4,5,6,7);
      ac = __builtin_amdgcn_mfma_f32_32x32x16_bf16(pa0, vf0, ac, 0, 0, 0);
      ac = __builtin_amdgcn_mfma_f32_32x32x16_bf16(pa1, vf1, ac, 0, 0, 0);
      if (act1) {
        short8 vf2 = __builtin_shufflevector(vlo[1][2], vhi[1][2], 0,1,2,3,4,5,6,7);
        short8 vf3 = __builtin_shufflevector(vlo[1][3], vhi[1][3], 0,1,2,3,4,5,6,7);
        ac = __builtin_amdgcn_mfma_f32_32x32x16_bf16(pa2, vf2, ac, 0, 0, 0);
        ac = __builtin_amdgcn_mfma_f32_32x32x16_bf16(pa3, vf3, ac, 0, 0, 0);
      }
    }
    __builtin_amdgcn_s_setprio(0);
  };

  // prologue: stage chunk 0 into buf 0
  { KV r0 = loadKV(0); writeKV(r0, 0); }
  __syncthreads();

  int cur = 0;
  for (int ch = 0; ch < nchB; ++ch) {
    const bool pref = (ch + 1 < nchB);
    KV nxt;
    if (pref) nxt = loadKV(ch + 1);

    // heavy tile first (always active), then light tile while it lasts
    doTile(ch, cur, q0B, qfB, accoB0, accoB1, acclB, mB);
    if (ch < nchA) doTile(ch, cur, q0A, qfA, accoA0, accoA1, acclA, mA);

    if (pref) writeKV(nxt, cur ^ 1);
    __syncthreads();
    cur ^= 1;
  }

  // ---- epilogue: O = acco / accl for both tiles ----
  auto epi = [&](int q0w, const f32x16& acco0, const f32x16& acco1, const f32x16& accl) {
#pragma unroll
    for (int r = 0; r < 16; ++r) {
      const int q_loc = (r & 3) + 8 * (r >> 2) + 4 * hi;
      const int q = q0w + q_loc;
      const float inv = 1.0f / accl[r];
      float* op = Og + (((size_t)(b * Lc + q)) * Hc + h) * Dc + q32;
      op[0]  = acco0[r] * inv;
      op[32] = acco1[r] * inv;
    }
  };
  epi(q0A, accoA0, accoA1, acclA);
  epi(q0B, accoB0, accoB1, acclB);
}

extern "C" void kernel_launch(void* const* d_in, const int* in_sizes, int n_in,
                              void* d_out, int out_size, void* d_ws, size_t ws_size,
                              hipStream_t stream) {
  const float* Q = (const float*)d_in[0];
  const float* K = (const float*)d_in[1];
  const float* V = (const float*)d_in[2];
  float* O = (float*)d_out;
  dim3 grid(Bc * Hc, NQT / 2);   // x = bh (64) -> XCD = bh % 8 ; y = pair (8)
  fattn_kernel<<<grid, 256, 0, stream>>>(Q, K, V, O);
}

// Round 19
// 93.194 us; speedup vs baseline: 1.0796x; 1.0190x over previous
//
#include <hip/hip_runtime.h>
#include <hip/hip_bf16.h>

typedef __attribute__((ext_vector_type(8))) short short8;
typedef __attribute__((ext_vector_type(4))) short short4v;
typedef __attribute__((ext_vector_type(16))) float f32x16;

constexpr int Bc = 4;
constexpr int Lc = 2048;
constexpr int Sc = 2048;
constexpr int Hc = 16;
constexpr int Ec = 64;
constexpr int Dc = 64;
constexpr int QBLK = 128;   // per tile: 4 waves x 32 q-rows; each block owns TWO tiles
constexpr int KBLK = 64;
constexpr int NQT  = Lc / QBLK;   // 16 q-tiles -> 8 complementary pairs

__device__ __forceinline__ unsigned short b16(float x) {
  __bf16 h = (__bf16)x;
  return __builtin_bit_cast(unsigned short, h);
}
__device__ __forceinline__ unsigned pk2(float lo, float hi) {
  return (unsigned)b16(lo) | ((unsigned)b16(hi) << 16);
}
__device__ __forceinline__ short8 cvt8(float4 a, float4 b) {
  short8 w;
  w[0] = (short)b16(a.x); w[1] = (short)b16(a.y);
  w[2] = (short)b16(a.z); w[3] = (short)b16(a.w);
  w[4] = (short)b16(b.x); w[5] = (short)b16(b.y);
  w[6] = (short)b16(b.z); w[7] = (short)b16(b.w);
  return w;
}
__device__ __forceinline__ short8 mk8(unsigned d0, unsigned d1, unsigned d2, unsigned d3) {
  union { unsigned u[4]; short8 s; } t;
  t.u[0] = d0; t.u[1] = d1; t.u[2] = d2; t.u[3] = d3;
  return t.s;
}
__device__ __forceinline__ float max3f(float a, float b, float c) {
  return fmaxf(fmaxf(a, b), c);   // clang fuses to v_max3_f32
}

struct KV { float4 k[4]; float4 v[4]; };

__global__ __launch_bounds__(256, 2)
void fattn_kernel(const float* __restrict__ Qg, const float* __restrict__ Kg,
                  const float* __restrict__ Vg, float* __restrict__ Og) {
  __shared__ unsigned short Kl[2][KBLK * 64];
  __shared__ unsigned short Vl[2][KBLK * 64];

  const int tid  = (int)threadIdx.x;
  const int wave = tid >> 6;
  const int lane = tid & 63;
  const int q32  = lane & 31;
  const int hi   = lane >> 5;

  // XCD-aware mapping (T1): x = bh (64), y = pair (8).
  // linear id = bh + 64*pb -> XCD = bh % 8: all 8 pair-blocks of one bh share
  // one XCD's L2 and walk K/V chunks in lock-step -> 1 miss + 7 hits per chunk.
  const int bh = (int)blockIdx.x;
  const int pb = (int)blockIdx.y;
  const int b  = bh >> 4;
  const int h  = bh & 15;

  const int qA   = pb;            // light tile
  const int qB   = NQT - 1 - pb;  // heavy tile
  const int q0A  = qA * QBLK + wave * 32;
  const int q0B  = qB * QBLK + wave * 32;
  const int nchA = 2 * pb + 2;
  const int nchB = 2 * qB + 2;    // >= nchA

  const float QSCALE = 0.125f * 1.44269504088896341f;  // 1/sqrt(64) * log2(e)
  auto loadQ = [&](int q0, short8 (&qf)[4]) {
    const float* qp = Qg + (((size_t)(b * Lc + q0 + q32)) * Hc + h) * Ec;
#pragma unroll
    for (int c = 0; c < 4; ++c) {
      const float4* p4 = (const float4*)(qp + c * 16 + hi * 8);
      float4 x = p4[0], y = p4[1];
      x.x *= QSCALE; x.y *= QSCALE; x.z *= QSCALE; x.w *= QSCALE;
      y.x *= QSCALE; y.y *= QSCALE; y.z *= QSCALE; y.w *= QSCALE;
      qf[c] = cvt8(x, y);
    }
  };
  short8 qfA[4], qfB[4];
  loadQ(q0A, qfA);
  loadQ(q0B, qfB);

  short8 ones;
#pragma unroll
  for (int j = 0; j < 8; ++j) ones[j] = (short)0x3F80;

  const int s  = tid >> 2;
  const int e0 = (tid & 3) << 4;

  auto loadKV = [&](int ch) {
    KV r;
    const size_t row = (((size_t)(b * Sc + ch * KBLK + s)) * Hc + h);
    const float4* kp4 = (const float4*)(Kg + row * Ec + e0);
    const float4* vp4 = (const float4*)(Vg + row * Dc + e0);
#pragma unroll
    for (int i = 0; i < 4; ++i) { r.k[i] = kp4[i]; r.v[i] = vp4[i]; }
    return r;
  };

  auto writeKV = [&](const KV& r, int buf) {
    short8 w0 = cvt8(r.k[0], r.k[1]);
    short8 w1 = cvt8(r.k[2], r.k[3]);
    const int c0 = e0 >> 3;
    *(short8*)&Kl[buf][s * 64 + (((c0    ) ^ (s & 7)) << 3)] = w0;
    *(short8*)&Kl[buf][s * 64 + (((c0 + 1) ^ (s & 7)) << 3)] = w1;
    short8 wv0 = cvt8(r.v[0], r.v[1]);
    short8 wv1 = cvt8(r.v[2], r.v[3]);
    const int vt = ((s >> 2) * 4 + (tid & 3)) * 64 + (s & 3) * 16;
    *(short8*)&Vl[buf][vt]     = wv0;
    *(short8*)&Vl[buf][vt + 8] = wv1;
  };

  f32x16 accoA0 = (f32x16)(0.f), accoA1 = (f32x16)(0.f), acclA = (f32x16)(0.f);
  f32x16 accoB0 = (f32x16)(0.f), accoB1 = (f32x16)(0.f), acclB = (f32x16)(0.f);
  float mA = -1e30f, mB = -1e30f;

  auto doTile = [&](int ch, int cur, int q0w, const short8 (&qf)[4],
                    f32x16& acco0, f32x16& acco1, f32x16& accl, float& m_run) {
    const int s0 = ch * 64;
    const bool act0 = (s0 <= q0w);
    if (!act0) return;
    const bool act1  = (s0 + 32 <= q0w);
    const bool diag0 = (s0 == q0w);
    const bool diag1 = (s0 + 32 == q0w);

    auto qk = [&](int sb) {
      f32x16 acc = (f32x16)(0.f);
      const int sr = sb * 32 + q32;
      const int rb = sr * 64;
      const int sw = sr & 7;
#pragma unroll
      for (int c = 0; c < 4; ++c) {
        short8 kf = *(const short8*)&Kl[cur][rb + (((2 * c + hi) ^ sw) << 3)];
        acc = __builtin_amdgcn_mfma_f32_32x32x16_bf16(kf, qf[c], acc, 0, 0, 0);
      }
      return acc;
    };
    f32x16 S0 = qk(0);
    f32x16 S1;
    if (act1) S1 = qk(1);

    const int tq = q32 - 4 * hi;
    if (diag0) {
#pragma unroll
      for (int r = 0; r < 16; ++r)
        if (((r & 3) + 8 * (r >> 2)) > tq) S0[r] = -1e30f;
    }
    if (act1 && diag1) {
#pragma unroll
      for (int r = 0; r < 16; ++r)
        if (((r & 3) + 8 * (r >> 2)) > tq) S1[r] = -1e30f;
    }

    // ---- chunk max via v_max3 tree (short dep chain) ----
    float pmax;
    {
      float t0 = max3f(S0[0],  S0[1],  S0[2]);
      float t1 = max3f(S0[3],  S0[4],  S0[5]);
      float t2 = max3f(S0[6],  S0[7],  S0[8]);
      float t3 = max3f(S0[9],  S0[10], S0[11]);
      float t4 = max3f(S0[12], S0[13], S0[14]);
      float u0 = max3f(t0, t1, t2);
      float u1 = max3f(t3, t4, S0[15]);
      pmax = fmaxf(u0, u1);
      if (act1) {
        float v0 = max3f(S1[0],  S1[1],  S1[2]);
        float v1 = max3f(S1[3],  S1[4],  S1[5]);
        float v2 = max3f(S1[6],  S1[7],  S1[8]);
        float v3 = max3f(S1[9],  S1[10], S1[11]);
        float v4 = max3f(S1[12], S1[13], S1[14]);
        float w0 = max3f(v0, v1, v2);
        float w1 = max3f(v3, v4, S1[15]);
        pmax = max3f(pmax, w0, w1);
      }
    }
    {
      unsigned px = __builtin_bit_cast(unsigned, pmax);
      auto sw = __builtin_amdgcn_permlane32_swap(px, px, false, false);
      pmax = fmaxf(__builtin_bit_cast(float, (unsigned)sw[0]),
                   __builtin_bit_cast(float, (unsigned)sw[1]));
    }

    if (!__all(pmax - m_run <= 8.0f)) {
      const float mnew  = fmaxf(m_run, pmax);
      const float alpha = exp2f(m_run - mnew);
      m_run = mnew;
      const int hib = hi << 4;
      const int av  = __builtin_bit_cast(int, alpha);
#pragma unroll
      for (int r = 0; r < 16; ++r) {
        const int addr = hib + 4 * ((r & 3) + 8 * (r >> 2));
        float ar = __builtin_bit_cast(float, __builtin_amdgcn_ds_bpermute(addr, av));
        acco0[r] *= ar; acco1[r] *= ar; accl[r] *= ar;
      }
    }

#pragma unroll
    for (int r = 0; r < 16; ++r) S0[r] = exp2f(S0[r] - m_run);
    if (act1) {
#pragma unroll
      for (int r = 0; r < 16; ++r) S1[r] = exp2f(S1[r] - m_run);
    }

    auto mkpa = [&](const f32x16& P, int a, int bidx) {
      unsigned A0 = pk2(P[4 * a + 0],    P[4 * a + 1]);
      unsigned A1 = pk2(P[4 * a + 2],    P[4 * a + 3]);
      unsigned B0 = pk2(P[4 * bidx + 0], P[4 * bidx + 1]);
      unsigned B1 = pk2(P[4 * bidx + 2], P[4 * bidx + 3]);
      auto r0 = __builtin_amdgcn_permlane32_swap(A0, B0, false, false);
      auto r1 = __builtin_amdgcn_permlane32_swap(A1, B1, false, false);
      return mk8((unsigned)r0[0], (unsigned)r1[0], (unsigned)r0[1], (unsigned)r1[1]);
    };
    short8 pa0 = mkpa(S0, 0, 1);
    short8 pa1 = mkpa(S0, 2, 3);
    short8 pa2, pa3;
    if (act1) { pa2 = mkpa(S1, 0, 1); pa3 = mkpa(S1, 2, 3); }

    // ---- V transpose-reads: dt OUTER so the oldest 8 (or 4) reads are dt=0 ----
    const unsigned vbase = (unsigned)(size_t)(&Vl[cur][0]);
    const unsigned vcol  = ((unsigned)(q32 & 15) << 3);
    short4v vlo[2][4], vhi[2][4];
#pragma unroll
    for (int dt = 0; dt < 2; ++dt) {
#pragma unroll
      for (int ks = 0; ks < 4; ++ks) {
        if (ks < 2 || act1) {
          const unsigned a0 = vbase +
            ((((unsigned)(4 * ks + 2 * hi) * 4u) + 2u * dt + (unsigned)(q32 >> 4)) << 7) + vcol;
          asm volatile("ds_read_b64_tr_b16 %0, %1 offset:0"   : "=&v"(vlo[dt][ks]) : "v"(a0));
          asm volatile("ds_read_b64_tr_b16 %0, %1 offset:512" : "=&v"(vhi[dt][ks]) : "v"(a0));
        }
      }
    }

    // ---- denominators (MFMA pipe, no vf dependency; hides tr-read latency) ----
    accl = __builtin_amdgcn_mfma_f32_32x32x16_bf16(pa0, ones, accl, 0, 0, 0);
    accl = __builtin_amdgcn_mfma_f32_32x32x16_bf16(pa1, ones, accl, 0, 0, 0);
    if (act1) {
      accl = __builtin_amdgcn_mfma_f32_32x32x16_bf16(pa2, ones, accl, 0, 0, 0);
      accl = __builtin_amdgcn_mfma_f32_32x32x16_bf16(pa3, ones, accl, 0, 0, 0);
    }

    // ---- counted drain: start dt=0 PV once its 8 (or 4) reads are done ----
    if (act1) { asm volatile("s_waitcnt lgkmcnt(8)" ::: "memory"); }
    else      { asm volatile("s_waitcnt lgkmcnt(4)" ::: "memory"); }
    __builtin_amdgcn_sched_barrier(0);

    __builtin_amdgcn_s_setprio(1);
    {
      f32x16& ac = acco0;
      short8 vf0 = __builtin_shufflevector(vlo[0][0], vhi[0][0], 0,1,2,3,4,5,6,7);
      short8 vf1 = __builtin_shufflevector(vlo[0][1], vhi[0][1], 0,1,2,3,4,5,6,7);
      ac = __builtin_amdgcn_mfma_f32_32x32x16_bf16(pa0, vf0, ac, 0, 0, 0);
      ac = __builtin_amdgcn_mfma_f32_32x32x16_bf16(pa1, vf1, ac, 0, 0, 0);
      if (act1) {
        short8 vf2 = __builtin_shufflevector(vlo[0][2], vhi[0][2], 0,1,2,3,4,5,6,7);
        short8 vf3 = __builtin_shufflevector(vlo[0][3], vhi[0][3], 0,1,2,3,4,5,6,7);
        ac = __builtin_amdgcn_mfma_f32_32x32x16_bf16(pa2, vf2, ac, 0, 0, 0);
        ac = __builtin_amdgcn_mfma_f32_32x32x16_bf16(pa3, vf3, ac, 0, 0, 0);
      }
    }
    __builtin_amdgcn_s_setprio(0);

    asm volatile("s_waitcnt lgkmcnt(0)" ::: "memory");
    __builtin_amdgcn_sched_barrier(0);

    __builtin_amdgcn_s_setprio(1);
    {
      f32x16& ac = acco1;
      short8 vf0 = __builtin_shufflevector(vlo[1][0], vhi[1][0], 0,1,2,3,4,5,6,7);
      short8 vf1 = __builtin_shufflevector(vlo[1][1], vhi[1][1], 0,1,2,3,4,5,6,7);
      ac = __builtin_amdgcn_mfma_f32_32x32x16_bf16(pa0, vf0, ac, 0, 0, 0);
      ac = __builtin_amdgcn_mfma_f32_32x32x16_bf16(pa1, vf1, ac, 0, 0, 0);
      if (act1) {
        short8 vf2 = __builtin_shufflevector(vlo[1][2], vhi[1][2], 0,1,2,3,4,5,6,7);
        short8 vf3 = __builtin_shufflevector(vlo[1][3], vhi[1][3], 0,1,2,3,4,5,6,7);
        ac = __builtin_amdgcn_mfma_f32_32x32x16_bf16(pa2, vf2, ac, 0, 0, 0);
        ac = __builtin_amdgcn_mfma_f32_32x32x16_bf16(pa3, vf3, ac, 0, 0, 0);
      }
    }
    __builtin_amdgcn_s_setprio(0);
  };

  // prologue: stage chunk 0 into buf 0; prefetch chunk 1 into registers
  { KV r0 = loadKV(0); writeKV(r0, 0); }
  KV nxt;
  if (1 < nchB) nxt = loadKV(1);
  __syncthreads();

  int cur = 0;
  for (int ch = 0; ch < nchB; ++ch) {
    // ---- write chunk ch+1 (staged last epoch) at epoch TOP: its ds_write
    // drain hides under this epoch's compute instead of extending the tail.
    // Safe under dbuf-2: previous epoch's reads of buf[cur^1] are separated
    // from this write by the inter-epoch barrier. ----
    if (ch + 1 < nchB) writeKV(nxt, cur ^ 1);
    // ---- prefetch distance 2: issue chunk ch+2 global loads ----
    if (ch + 2 < nchB) nxt = loadKV(ch + 2);

    // heavy tile first (always active), then light tile while it lasts
    doTile(ch, cur, q0B, qfB, accoB0, accoB1, acclB, mB);
    if (ch < nchA) doTile(ch, cur, q0A, qfA, accoA0, accoA1, acclA, mA);

    __syncthreads();
    cur ^= 1;
  }

  // ---- epilogue: O = acco / accl for both tiles ----
  auto epi = [&](int q0w, const f32x16& acco0, const f32x16& acco1, const f32x16& accl) {
#pragma unroll
    for (int r = 0; r < 16; ++r) {
      const int q_loc = (r & 3) + 8 * (r >> 2) + 4 * hi;
      const int q = q0w + q_loc;
      const float inv = 1.0f / accl[r];
      float* op = Og + (((size_t)(b * Lc + q)) * Hc + h) * Dc + q32;
      op[0]  = acco0[r] * inv;
      op[32] = acco1[r] * inv;
    }
  };
  epi(q0A, accoA0, accoA1, acclA);
  epi(q0B, accoB0, accoB1, acclB);
}

extern "C" void kernel_launch(void* const* d_in, const int* in_sizes, int n_in,
                              void* d_out, int out_size, void* d_ws, size_t ws_size,
                              hipStream_t stream) {
  const float* Q = (const float*)d_in[0];
  const float* K = (const float*)d_in[1];
  const float* V = (const float*)d_in[2];
  float* O = (float*)d_out;
  dim3 grid(Bc * Hc, NQT / 2);   // x = bh (64) -> XCD = bh % 8 ; y = pair (8)
  fattn_kernel<<<grid, 256, 0, stream>>>(Q, K, V, O);
}